// Round 1
// baseline (524.373 us; speedup 1.0000x reference)
//
#include <hip/hip_runtime.h>
#include <hip/hip_bf16.h>

#define BTOT 32768
#define TB 32

// ---------------------------------------------------------------------------
// Folded attention weights: M[h][jq][j] = sum_d Wq[h][jq][d] * Wk[h][j][d]
// stored as M[jq*512 + h*128 + j]  (4*64*128 = 32768 floats in d_ws)
// ---------------------------------------------------------------------------
__global__ __launch_bounds__(256) void precompute_M(
        const float* __restrict__ Wk, const float* __restrict__ Wq,
        float* __restrict__ M)
{
    int tid = blockIdx.x * 256 + threadIdx.x;   // 32768 total
    int h   = tid >> 13;
    int rem = tid & 8191;
    int jq  = rem >> 7;
    int j   = rem & 127;
    const float* q = Wq + (h*64 + jq)*32;
    const float* k = Wk + (h*128 + j)*32;
    float acc = 0.f;
#pragma unroll
    for (int d = 0; d < 32; d += 4) {
        float4 a = *(const float4*)(q + d);
        float4 b = *(const float4*)(k + d);
        acc += a.x*b.x + a.y*b.y + a.z*b.z + a.w*b.w;
    }
    M[jq*512 + h*128 + j] = acc;
}

// round-to-nearest-even f32 -> bf16 (stored as ushort)
static __device__ __forceinline__ unsigned short f2bf(float x) {
    unsigned int u = __float_as_uint(x);
    u = (u + 0x7fffu + ((u >> 16) & 1u)) >> 16;
    return (unsigned short)u;
}
static __device__ __forceinline__ float bflo(unsigned int u) {
    return __uint_as_float(u << 16);
}
static __device__ __forceinline__ float bfhi(unsigned int u) {
    return __uint_as_float(u & 0xffff0000u);
}

// ---------------------------------------------------------------------------
// Fully fused critic: self MLP + folded-key t + streaming agent loop with
// online softmax + final projection. One block = 32 batch rows, 256 threads.
// LDS (69248 B -> 2 blocks/CU):
//   sE   [0..16896)    32x132 f32: enc tile; also sX (stride 84) in self phase
//   sU   [16896..33792) 32x132 f32: sX1 (68) / sIn (84) / normalized-ov (132)
//   sT   [33792..67200) 32x522 bf16: t vectors; first 8704 B doubles as sX2
//   stats[67200..69248) m / s / alpha / p, each 32x4 f32
// ---------------------------------------------------------------------------
__global__ __launch_bounds__(256, 2) void fused_critic(
    const float* __restrict__ state_one, const float* __restrict__ act_one,
    const float* __restrict__ state_others, const float* __restrict__ act_others,
    const float* __restrict__ W1, const float* __restrict__ b1,
    const float* __restrict__ W2, const float* __restrict__ b2,
    const float* __restrict__ w3_self, const float* __restrict__ We,
    const float* __restrict__ be, const float* __restrict__ Wv,
    const float* __restrict__ bvv, const float* __restrict__ w3_others,
    const float* __restrict__ Wout, const float* __restrict__ bout,
    const float* __restrict__ M, float* __restrict__ out)
{
    __shared__ __align__(16) unsigned char smem[69248];
    float*          sE     = (float*)smem;
    float*          sU     = (float*)(smem + 16896);
    unsigned short* sT     = (unsigned short*)(smem + 33792);
    float*          sMv    = (float*)(smem + 67200);
    float*          sSv    = sMv + 128;
    float*          sAv    = sMv + 256;
    float*          sPv    = sMv + 384;

    const int t  = threadIdx.x;
    const int b0 = blockIdx.x * TB;

    // ---- phase 0: stage self input [32 x 78] into sX (=sE, stride 84) ----
    float* sX = sE;
    for (int f = t; f < TB*16; f += 256) {
        int r = f >> 4, c4 = (f & 15) << 2;
        *(float4*)(sX + r*84 + c4) =
            *(const float4*)(state_one + (size_t)(b0 + r)*64 + c4);
    }
    for (int f = t; f < TB*14; f += 256) {
        int r = f / 14, c = f - r*14;
        sX[r*84 + 64 + c] = act_one[(size_t)(b0 + r)*14 + c];
    }
    if (t < 128) { sMv[t] = -1e30f; sSv[t] = 0.f; }
    __syncthreads();

    const int cg = t & 15, rg = t >> 4;   // 16x16 map: 2 rows x 4 cols
    const int c0 = cg << 2;
    float* sX1 = sU;                      // stride 68

    // ---- phase 1: x1 = relu(x @ W1 + b1)  [K=78, N=64] ----
    {
        float acc[2][4] = {};
#pragma unroll 2
        for (int k = 0; k < 78; ++k) {
            float4 w = *(const float4*)(W1 + k*64 + c0);
            float a0 = sX[(rg*2+0)*84 + k];
            float a1 = sX[(rg*2+1)*84 + k];
            acc[0][0] += a0*w.x; acc[0][1] += a0*w.y; acc[0][2] += a0*w.z; acc[0][3] += a0*w.w;
            acc[1][0] += a1*w.x; acc[1][1] += a1*w.y; acc[1][2] += a1*w.z; acc[1][3] += a1*w.w;
        }
        float4 bb = *(const float4*)(b1 + c0);
#pragma unroll
        for (int i = 0; i < 2; ++i) {
            int r = rg*2 + i;
            sX1[r*68 + c0+0] = fmaxf(acc[i][0] + bb.x, 0.f);
            sX1[r*68 + c0+1] = fmaxf(acc[i][1] + bb.y, 0.f);
            sX1[r*68 + c0+2] = fmaxf(acc[i][2] + bb.z, 0.f);
            sX1[r*68 + c0+3] = fmaxf(acc[i][3] + bb.w, 0.f);
        }
    }
    __syncthreads();

    float* sX2 = (float*)(smem + 33792);  // alias over sT region, stride 68
    // ---- phase 2: x2 = relu(x1 @ W2 + b2)  [K=64, N=64] ----
    {
        float acc[2][4] = {};
#pragma unroll 4
        for (int k = 0; k < 64; ++k) {
            float4 w = *(const float4*)(W2 + k*64 + c0);
            float a0 = sX1[(rg*2+0)*68 + k];
            float a1 = sX1[(rg*2+1)*68 + k];
            acc[0][0] += a0*w.x; acc[0][1] += a0*w.y; acc[0][2] += a0*w.z; acc[0][3] += a0*w.w;
            acc[1][0] += a1*w.x; acc[1][1] += a1*w.y; acc[1][2] += a1*w.z; acc[1][3] += a1*w.w;
        }
        float4 bb = *(const float4*)(b2 + c0);
#pragma unroll
        for (int i = 0; i < 2; ++i) {
            int r = rg*2 + i;
            sX2[r*68 + c0+0] = fmaxf(acc[i][0] + bb.x, 0.f);
            sX2[r*68 + c0+1] = fmaxf(acc[i][1] + bb.y, 0.f);
            sX2[r*68 + c0+2] = fmaxf(acc[i][2] + bb.z, 0.f);
            sX2[r*68 + c0+3] = fmaxf(acc[i][3] + bb.w, 0.f);
        }
    }
    __syncthreads();

    // ---- phase 3: x3_self fragment kept in registers (same map as final) ----
    float x3s[2][4] = {};
    {
#pragma unroll 4
        for (int k = 0; k < 64; ++k) {
            float4 w = *(const float4*)(w3_self + k*64 + c0);
            float a0 = sX2[(rg*2+0)*68 + k];
            float a1 = sX2[(rg*2+1)*68 + k];
            x3s[0][0] += a0*w.x; x3s[0][1] += a0*w.y; x3s[0][2] += a0*w.z; x3s[0][3] += a0*w.w;
            x3s[1][0] += a1*w.x; x3s[1][1] += a1*w.y; x3s[1][2] += a1*w.z; x3s[1][3] += a1*w.w;
        }
    }
    __syncthreads();   // done reading sX2 before sT is written

    // ---- phase 4: t = x1 @ M  -> sT bf16, layout [r*522 + h*128 + j] ----
    {
        float acc[8][2][4] = {};   // 8 column passes of 64, all in regs
        for (int k = 0; k < 64; ++k) {
            float a0 = sX1[(rg*2+0)*68 + k];
            float a1 = sX1[(rg*2+1)*68 + k];
            const float* mrow = M + k*512 + c0;
#pragma unroll
            for (int p = 0; p < 8; ++p) {
                float4 w = *(const float4*)(mrow + p*64);
                acc[p][0][0] += a0*w.x; acc[p][0][1] += a0*w.y; acc[p][0][2] += a0*w.z; acc[p][0][3] += a0*w.w;
                acc[p][1][0] += a1*w.x; acc[p][1][1] += a1*w.y; acc[p][1][2] += a1*w.z; acc[p][1][3] += a1*w.w;
            }
        }
#pragma unroll
        for (int p = 0; p < 8; ++p) {
            int cc = p*64 + c0;
#pragma unroll
            for (int i = 0; i < 2; ++i) {
                int r = rg*2 + i;
                sT[r*522 + cc+0] = f2bf(acc[p][i][0]);
                sT[r*522 + cc+1] = f2bf(acc[p][i][1]);
                sT[r*522 + cc+2] = f2bf(acc[p][i][2]);
                sT[r*522 + cc+3] = f2bf(acc[p][i][3]);
            }
        }
    }

    // ---- agent loop ----
    const int vcg = t & 31, vrg = t >> 5;  // 32 cgs x 8 rgs (4 rows x 4 cols)
    const int vc0 = vcg << 2;
    const int vh  = vcg >> 3;
    const int vd0 = vc0 & 31;
    float o[4][4] = {};
    float* sIn = sU;                       // stride 84

    for (int a = 0; a < 7; ++a) {
        __syncthreads();   // protects sU (sX1/sIn) and sE across iterations
        // stage other-agent input [32 x 82]
        const float* sa = state_others + ((size_t)a*BTOT + b0)*64;
        for (int f = t; f < TB*16; f += 256) {
            int r = f >> 4, c4 = (f & 15) << 2;
            *(float4*)(sIn + r*84 + c4) = *(const float4*)(sa + (size_t)r*64 + c4);
        }
        const float* aa = act_others + ((size_t)a*BTOT + b0)*18;
        for (int f = t; f < TB*18; f += 256) {
            int r = f / 18, c = f - r*18;
            sIn[r*84 + 64 + c] = aa[(size_t)r*18 + c];
        }
        __syncthreads();

        // enc = relu(inp @ We_a + be_a)  [K=82, N=128] -> sE
        {
            float acc[4][4] = {};
            const float* w = We + (size_t)a*82*128 + vc0;
#pragma unroll 2
            for (int k = 0; k < 82; ++k) {
                float4 w4 = *(const float4*)(w + k*128);
#pragma unroll
                for (int i = 0; i < 4; ++i) {
                    float av = sIn[(vrg*4+i)*84 + k];
                    acc[i][0] += av*w4.x; acc[i][1] += av*w4.y;
                    acc[i][2] += av*w4.z; acc[i][3] += av*w4.w;
                }
            }
            float4 bb = *(const float4*)(be + a*128 + vc0);
#pragma unroll
            for (int i = 0; i < 4; ++i) {
                int r = vrg*4 + i;
                float4 v;
                v.x = fmaxf(acc[i][0] + bb.x, 0.f);
                v.y = fmaxf(acc[i][1] + bb.y, 0.f);
                v.z = fmaxf(acc[i][2] + bb.z, 0.f);
                v.w = fmaxf(acc[i][3] + bb.w, 0.f);
                *(float4*)(sE + r*132 + vc0) = v;
            }
        }
        __syncthreads();

        // logits + online softmax stats: wave h handles head h;
        // lane = (b_l, half): 64-element half-dot, reduce via shfl_xor(32)
        {
            int h    = t >> 6;
            int lane = t & 63;
            int b_l  = lane & 31;
            int half = lane >> 5;
            const unsigned int* tq =
                (const unsigned int*)(sT + b_l*522 + h*128 + half*64);
            const float* ep = sE + b_l*132 + half*64;
            float part = 0.f;
#pragma unroll
            for (int jj = 0; jj < 64; jj += 4) {
                float4 e4 = *(const float4*)(ep + jj);
                unsigned int u0 = tq[(jj>>1)+0];
                unsigned int u1 = tq[(jj>>1)+1];
                part += e4.x*bflo(u0) + e4.y*bfhi(u0)
                      + e4.z*bflo(u1) + e4.w*bfhi(u1);
            }
            part += __shfl_xor(part, 32);
            if (half == 0) {
                float l  = part * 0.17677669529663687f;  // 1/sqrt(32)
                int idx  = b_l*4 + h;
                float mo = sMv[idx];
                float mn = fmaxf(mo, l);
                float al = __expf(mo - mn);
                float p  = __expf(l - mn);
                sSv[idx] = sSv[idx]*al + p;
                sMv[idx] = mn;
                sAv[idx] = al;
                sPv[idx] = p;
            }
        }
        __syncthreads();

        // vals = relu(enc @ Wv + bv); online accumulate o = o*alpha + p*val
        {
            float acc[4][4] = {};
            const float* w = Wv + (size_t)vh*4096 + vd0;
#pragma unroll 4
            for (int k = 0; k < 128; ++k) {
                float4 w4 = *(const float4*)(w + k*32);
#pragma unroll
                for (int i = 0; i < 4; ++i) {
                    float av = sE[(vrg*4+i)*132 + k];
                    acc[i][0] += av*w4.x; acc[i][1] += av*w4.y;
                    acc[i][2] += av*w4.z; acc[i][3] += av*w4.w;
                }
            }
            float4 bb = *(const float4*)(bvv + vh*32 + vd0);
#pragma unroll
            for (int i = 0; i < 4; ++i) {
                int r = vrg*4 + i;
                float al = sAv[r*4 + vh], p = sPv[r*4 + vh];
                o[i][0] = o[i][0]*al + p*fmaxf(acc[i][0] + bb.x, 0.f);
                o[i][1] = o[i][1]*al + p*fmaxf(acc[i][1] + bb.y, 0.f);
                o[i][2] = o[i][2]*al + p*fmaxf(acc[i][2] + bb.z, 0.f);
                o[i][3] = o[i][3]*al + p*fmaxf(acc[i][3] + bb.w, 0.f);
            }
        }
    }
    __syncthreads();

    // ---- normalize ov and dump to sU (stride 132) ----
    {
#pragma unroll
        for (int i = 0; i < 4; ++i) {
            int r = vrg*4 + i;
            float inv = 1.0f / sSv[r*4 + vh];
            float4 v;
            v.x = o[i][0]*inv; v.y = o[i][1]*inv;
            v.z = o[i][2]*inv; v.w = o[i][3]*inv;
            *(float4*)(sU + r*132 + vc0) = v;
        }
    }
    __syncthreads();

    // ---- final: x3o = ov @ w3_others; out = relu(x3s+x3o) . Wout + bout ----
    {
        float acc[2][4] = {};
#pragma unroll 4
        for (int k = 0; k < 128; ++k) {
            float4 w4 = *(const float4*)(w3_others + k*64 + c0);
            float a0 = sU[(rg*2+0)*132 + k];
            float a1 = sU[(rg*2+1)*132 + k];
            acc[0][0] += a0*w4.x; acc[0][1] += a0*w4.y; acc[0][2] += a0*w4.z; acc[0][3] += a0*w4.w;
            acc[1][0] += a1*w4.x; acc[1][1] += a1*w4.y; acc[1][2] += a1*w4.z; acc[1][3] += a1*w4.w;
        }
        float4 wo = *(const float4*)(Wout + c0);
        float bo = bout[0];
#pragma unroll
        for (int i = 0; i < 2; ++i) {
            float p = fmaxf(acc[i][0] + x3s[i][0], 0.f) * wo.x
                    + fmaxf(acc[i][1] + x3s[i][1], 0.f) * wo.y
                    + fmaxf(acc[i][2] + x3s[i][2], 0.f) * wo.z
                    + fmaxf(acc[i][3] + x3s[i][3], 0.f) * wo.w;
#pragma unroll
            for (int off = 1; off < 16; off <<= 1)
                p += __shfl_xor(p, off);
            if (cg == 0) out[b0 + rg*2 + i] = p + bo;
        }
    }
}

extern "C" void kernel_launch(void* const* d_in, const int* in_sizes, int n_in,
                              void* d_out, int out_size, void* d_ws, size_t ws_size,
                              hipStream_t stream) {
    (void)in_sizes; (void)n_in; (void)out_size; (void)ws_size;
    const float* state_one    = (const float*)d_in[0];
    const float* act_one      = (const float*)d_in[1];
    const float* state_others = (const float*)d_in[2];
    const float* act_others   = (const float*)d_in[3];
    const float* W1           = (const float*)d_in[4];
    const float* b1           = (const float*)d_in[5];
    const float* W2           = (const float*)d_in[6];
    const float* b2           = (const float*)d_in[7];
    const float* w3_self      = (const float*)d_in[8];
    const float* We           = (const float*)d_in[9];
    const float* be           = (const float*)d_in[10];
    const float* Wk           = (const float*)d_in[11];
    const float* Wq           = (const float*)d_in[12];
    const float* Wv           = (const float*)d_in[13];
    const float* bv           = (const float*)d_in[14];
    const float* w3_others    = (const float*)d_in[15];
    const float* Wout         = (const float*)d_in[16];
    const float* bout         = (const float*)d_in[17];
    float* out = (float*)d_out;
    float* M   = (float*)d_ws;   // 32768 floats

    precompute_M<<<128, 256, 0, stream>>>(Wk, Wq, M);
    fused_critic<<<BTOT/TB, 256, 0, stream>>>(
        state_one, act_one, state_others, act_others,
        W1, b1, W2, b2, w3_self, We, be, Wv, bv, w3_others, Wout, bout,
        M, out);
}

// Round 4
// 457.300 us; speedup vs baseline: 1.1467x; 1.1467x over previous
//
#include <hip/hip_runtime.h>
#include <hip/hip_bf16.h>

#define BTOT 32768
#define TB 32

typedef __attribute__((ext_vector_type(8))) short bhalf8;   // 8 bf16 = 4 VGPRs
typedef __attribute__((ext_vector_type(4))) float f32x4;    // MFMA acc

static __device__ __forceinline__ unsigned short f2bf(float x) {
    unsigned int u = __float_as_uint(x);
    u = (u + 0x7fffu + ((u >> 16) & 1u)) >> 16;
    return (unsigned short)u;
}
static __device__ __forceinline__ float bf2f(unsigned short s) {
    return __uint_as_float(((unsigned int)s) << 16);
}
static __device__ __forceinline__ float bflo(unsigned int u) {
    return __uint_as_float(u << 16);
}
static __device__ __forceinline__ float bfhi(unsigned int u) {
    return __uint_as_float(u & 0xffff0000u);
}

// ---------------------------------------------------------------------------
// Weight preprocessing into MFMA B-fragment-linear SPLIT bf16 (hi|lo).
// B-frag for (kt, nt): lane l holds B[k=kt*32+(l>>4)*8+j][n=nt*16+(l&15)],
// hi at idx = ((nt*KT+kt)*64 + l)*16 + j, lo at +8+j.
// ws: Mf2  @0       131072 B (M[64 x 512] split, KT=2, NT=32)
//     Wef2 @131072  344064 B (per agent We[96 x 128] split, KT=3, NT=8)
//     Wvf2 @475136  65536 B  (Wv as [128 x 128], n=h*32+d, split, KT=4, NT=8)
// ---------------------------------------------------------------------------
__global__ __launch_bounds__(256) void fold_M_frag(
        const float* __restrict__ Wk, const float* __restrict__ Wq,
        unsigned short* __restrict__ Mf2)
{
    int tid = blockIdx.x * 256 + threadIdx.x;   // 32768
    int h  = tid >> 13;
    int jq = (tid >> 7) & 63;
    int j  = tid & 127;
    const float* q = Wq + (h*64 + jq)*32;
    const float* k = Wk + (h*128 + j)*32;
    float acc = 0.f;
#pragma unroll
    for (int d = 0; d < 32; d += 4) {
        float4 a = *(const float4*)(q + d);
        float4 b = *(const float4*)(k + d);
        acc += a.x*b.x + a.y*b.y + a.z*b.z + a.w*b.w;
    }
    unsigned short hi = f2bf(acc);
    unsigned short lo = f2bf(acc - bf2f(hi));
    int n  = h*128 + j;
    int kt = jq >> 5, qd = (jq >> 3) & 3, jj = jq & 7;
    int nt = n >> 4,  ln = n & 15;
    size_t base = (((nt*2 + kt)*64) + qd*16 + ln)*16;
    Mf2[base + jj]     = hi;
    Mf2[base + 8 + jj] = lo;
}

__global__ __launch_bounds__(256) void conv_We(
        const float* __restrict__ We, unsigned short* __restrict__ Wef2)
{
    int tid = blockIdx.x * 256 + threadIdx.x;   // 7*96*128 = 86016
    int a = tid / 12288;
    int r = tid - a*12288;
    int k = r >> 7;          // 0..95
    int n = r & 127;
    float v = (k < 82) ? We[((size_t)a*82 + k)*128 + n] : 0.f;
    unsigned short hi = f2bf(v);
    unsigned short lo = f2bf(v - bf2f(hi));
    int kt = k >> 5, qd = (k >> 3) & 3, j = k & 7;
    int nt = n >> 4, ln = n & 15;
    size_t base = (size_t)a*24576 + (((nt*3 + kt)*64) + qd*16 + ln)*16;
    Wef2[base + j]     = hi;
    Wef2[base + 8 + j] = lo;
}

__global__ __launch_bounds__(256) void conv_Wv(
        const float* __restrict__ Wv, unsigned short* __restrict__ Wvf2)
{
    int tid = blockIdx.x * 256 + threadIdx.x;   // 4*128*32 = 16384
    int h = tid >> 12;
    int j = (tid >> 5) & 127;
    int d = tid & 31;
    float v = Wv[tid];
    unsigned short hi = f2bf(v);
    unsigned short lo = f2bf(v - bf2f(hi));
    int k = j, n = h*32 + d;
    int kt = k >> 5, qd = (k >> 3) & 3, jj = k & 7;
    int nt = n >> 4, ln = n & 15;
    size_t base = (((nt*4 + kt)*64) + qd*16 + ln)*16;
    Wvf2[base + jj]     = hi;
    Wvf2[base + 8 + jj] = lo;
}

// ---------------------------------------------------------------------------
// Fused critic. TB=32 rows/block, 256 threads (4 waves), 1024 blocks.
// All GEMMs feeding the output use split-bf16 (hi+lo) 3-term MFMA (~f32).
// Logits use f32 enc × bf16 t — exactly round 1's (1-ULP) numerics.
// LDS 49664 B -> 3 blocks/CU:
//   self : sX f32[32x84]@0, sX1 f32[32x68]@10752, sX2 f32[32x68]@19456,
//          sX1bH bf16[32x72]@28160, sX1bL @32768
//   t    : sT bf16[32x520]@0 (freed after tq reg load)
//   agent: sInH bf16[32x104]@0, sInL @6656, sEnH bf16[32x136]@13312,
//          sEnL @22016, sEf32 f32[32x132]@30720
//   final: sOv f32[32x132]@0
//   stats @47616: m/s/alpha/p, each 32x4 f32
// ---------------------------------------------------------------------------
__global__ __launch_bounds__(256, 3) void fused_critic(
    const float* __restrict__ state_one, const float* __restrict__ act_one,
    const float* __restrict__ state_others, const float* __restrict__ act_others,
    const float* __restrict__ W1, const float* __restrict__ b1,
    const float* __restrict__ W2, const float* __restrict__ b2,
    const float* __restrict__ w3_self, const float* __restrict__ be,
    const float* __restrict__ bvp, const float* __restrict__ w3_others,
    const float* __restrict__ Wout, const float* __restrict__ bout,
    const unsigned short* __restrict__ Mf2, const unsigned short* __restrict__ Wef2,
    const unsigned short* __restrict__ Wvf2, float* __restrict__ out)
{
    __shared__ __align__(16) unsigned char smem[49664];
    float*          sX    = (float*)smem;                    // stride 84
    float*          sX1   = (float*)(smem + 10752);          // stride 68
    float*          sX2   = (float*)(smem + 19456);          // stride 68
    unsigned short* sX1bH = (unsigned short*)(smem + 28160); // stride 72
    unsigned short* sX1bL = (unsigned short*)(smem + 32768); // stride 72
    unsigned short* sT    = (unsigned short*)smem;           // stride 520
    unsigned short* sInH  = (unsigned short*)smem;           // stride 104
    unsigned short* sInL  = (unsigned short*)(smem + 6656);  // stride 104
    unsigned short* sEnH  = (unsigned short*)(smem + 13312); // stride 136
    unsigned short* sEnL  = (unsigned short*)(smem + 22016); // stride 136
    float*          sEf   = (float*)(smem + 30720);          // stride 132
    float*          sOv   = (float*)smem;                    // stride 132
    float*          sMv   = (float*)(smem + 47616);
    float*          sSv   = sMv + 128;
    float*          sAv   = sMv + 256;
    float*          sPv   = sMv + 384;

    const int t  = threadIdx.x;
    const int b0 = blockIdx.x * TB;
    const int w  = t >> 6;        // wave = head
    const int l  = t & 63;
    const int m  = l & 15;        // MFMA A row / C col
    const int qd = l >> 4;        // quad

    // ---- stage self input [32 x 78] f32 ----
    for (int f = t; f < TB*16; f += 256) {
        int r = f >> 4, c4 = (f & 15) << 2;
        *(float4*)(sX + r*84 + c4) =
            *(const float4*)(state_one + (size_t)(b0 + r)*64 + c4);
    }
    for (int f = t; f < TB*14; f += 256) {
        int r = f / 14, c = f - r*14;
        sX[r*84 + 64 + c] = act_one[(size_t)(b0 + r)*14 + c];
    }
    if (t < 128) { sMv[t] = -1e30f; sSv[t] = 0.f; }
    __syncthreads();

    const int cg = t & 15, rg = t >> 4;   // self/final map: 2 rows x 4 cols
    const int c0 = cg << 2;

    // ---- phase 1: x1 = relu(x @ W1 + b1) -> sX1 f32 + split bf16 ----
    {
        float acc[2][4] = {};
#pragma unroll 2
        for (int k = 0; k < 78; ++k) {
            float4 wv = *(const float4*)(W1 + k*64 + c0);
            float a0 = sX[(rg*2+0)*84 + k];
            float a1 = sX[(rg*2+1)*84 + k];
            acc[0][0] += a0*wv.x; acc[0][1] += a0*wv.y; acc[0][2] += a0*wv.z; acc[0][3] += a0*wv.w;
            acc[1][0] += a1*wv.x; acc[1][1] += a1*wv.y; acc[1][2] += a1*wv.z; acc[1][3] += a1*wv.w;
        }
        float4 bb = *(const float4*)(b1 + c0);
#pragma unroll
        for (int i = 0; i < 2; ++i) {
            int r = rg*2 + i;
            float v[4];
            v[0] = fmaxf(acc[i][0] + bb.x, 0.f);
            v[1] = fmaxf(acc[i][1] + bb.y, 0.f);
            v[2] = fmaxf(acc[i][2] + bb.z, 0.f);
            v[3] = fmaxf(acc[i][3] + bb.w, 0.f);
#pragma unroll
            for (int e = 0; e < 4; ++e) {
                sX1[r*68 + c0+e] = v[e];
                unsigned short hh = f2bf(v[e]);
                sX1bH[r*72 + c0+e] = hh;
                sX1bL[r*72 + c0+e] = f2bf(v[e] - bf2f(hh));
            }
        }
    }
    __syncthreads();

    // ---- phase 2: x2 = relu(x1 @ W2 + b2) -> sX2 f32 ----
    {
        float acc[2][4] = {};
#pragma unroll 4
        for (int k = 0; k < 64; ++k) {
            float4 wv = *(const float4*)(W2 + k*64 + c0);
            float a0 = sX1[(rg*2+0)*68 + k];
            float a1 = sX1[(rg*2+1)*68 + k];
            acc[0][0] += a0*wv.x; acc[0][1] += a0*wv.y; acc[0][2] += a0*wv.z; acc[0][3] += a0*wv.w;
            acc[1][0] += a1*wv.x; acc[1][1] += a1*wv.y; acc[1][2] += a1*wv.z; acc[1][3] += a1*wv.w;
        }
        float4 bb = *(const float4*)(b2 + c0);
#pragma unroll
        for (int i = 0; i < 2; ++i) {
            int r = rg*2 + i;
            sX2[r*68 + c0+0] = fmaxf(acc[i][0] + bb.x, 0.f);
            sX2[r*68 + c0+1] = fmaxf(acc[i][1] + bb.y, 0.f);
            sX2[r*68 + c0+2] = fmaxf(acc[i][2] + bb.z, 0.f);
            sX2[r*68 + c0+3] = fmaxf(acc[i][3] + bb.w, 0.f);
        }
    }
    __syncthreads();

    // ---- phase 3: x3_self fragment in registers (final-phase map) ----
    float x3s[2][4] = {};
    {
#pragma unroll 4
        for (int k = 0; k < 64; ++k) {
            float4 wv = *(const float4*)(w3_self + k*64 + c0);
            float a0 = sX2[(rg*2+0)*68 + k];
            float a1 = sX2[(rg*2+1)*68 + k];
            x3s[0][0] += a0*wv.x; x3s[0][1] += a0*wv.y; x3s[0][2] += a0*wv.z; x3s[0][3] += a0*wv.w;
            x3s[1][0] += a1*wv.x; x3s[1][1] += a1*wv.y; x3s[1][2] += a1*wv.z; x3s[1][3] += a1*wv.w;
        }
    }

    // ---- phase 4: t = x1 @ M, split 3-term MFMA (~f32), -> sT bf16 ----
    {
        f32x4 tacc[2][8] = {};
#pragma unroll
        for (int kt = 0; kt < 2; ++kt) {
            bhalf8 ah0 = *(const bhalf8*)(sX1bH + m*72      + kt*32 + qd*8);
            bhalf8 ah1 = *(const bhalf8*)(sX1bH + (16+m)*72 + kt*32 + qd*8);
            bhalf8 al0 = *(const bhalf8*)(sX1bL + m*72      + kt*32 + qd*8);
            bhalf8 al1 = *(const bhalf8*)(sX1bL + (16+m)*72 + kt*32 + qd*8);
#pragma unroll
            for (int nt2 = 0; nt2 < 8; ++nt2) {
                int nt = w*8 + nt2;
                const unsigned short* bp = Mf2 + ((nt*2 + kt)*64 + l)*16;
                bhalf8 bh = *(const bhalf8*)(bp);
                bhalf8 bl = *(const bhalf8*)(bp + 8);
                tacc[0][nt2] = __builtin_amdgcn_mfma_f32_16x16x32_bf16(ah0, bh, tacc[0][nt2], 0, 0, 0);
                tacc[1][nt2] = __builtin_amdgcn_mfma_f32_16x16x32_bf16(ah1, bh, tacc[1][nt2], 0, 0, 0);
                tacc[0][nt2] = __builtin_amdgcn_mfma_f32_16x16x32_bf16(ah0, bl, tacc[0][nt2], 0, 0, 0);
                tacc[1][nt2] = __builtin_amdgcn_mfma_f32_16x16x32_bf16(ah1, bl, tacc[1][nt2], 0, 0, 0);
                tacc[0][nt2] = __builtin_amdgcn_mfma_f32_16x16x32_bf16(al0, bh, tacc[0][nt2], 0, 0, 0);
                tacc[1][nt2] = __builtin_amdgcn_mfma_f32_16x16x32_bf16(al1, bh, tacc[1][nt2], 0, 0, 0);
            }
        }
        __syncthreads();   // all reads of sX1b*/sX2 done before sT overwrite
#pragma unroll
        for (int rt = 0; rt < 2; ++rt)
#pragma unroll
            for (int nt2 = 0; nt2 < 8; ++nt2)
#pragma unroll
                for (int r = 0; r < 4; ++r)
                    sT[(rt*16 + qd*4 + r)*520 + w*128 + nt2*16 + m] =
                        f2bf(tacc[rt][nt2][r]);
    }
    __syncthreads();

    // ---- load this thread's t-slice into registers ----
    const int b_l = l & 31, half = l >> 5;
    uint4 tq[8];
    {
        const uint4* tp4 = (const uint4*)(sT + b_l*520 + w*128 + half*64);
#pragma unroll
        for (int i = 0; i < 8; ++i) tq[i] = tp4[i];
    }
    __syncthreads();   // sT region free for sInH/sInL

    // zero-pad sIn cols 80..95 once (staging rewrites 0..81 each agent)
    for (int f = t; f < TB*16; f += 256) {
        int r = f >> 4, c = f & 15;
        sInH[r*104 + 80 + c] = 0;
        sInL[r*104 + 80 + c] = 0;
    }

    const float bv0 = bvp[w*32 + m];
    const float bv1 = bvp[w*32 + 16 + m];
    f32x4 o4[2][2] = {};

    for (int a = 0; a < 7; ++a) {
        __syncthreads();
        // ---- stage other-agent input f32 -> split bf16 LDS ----
        const float* sa = state_others + ((size_t)a*BTOT + b0)*64;
        for (int f = t; f < TB*16; f += 256) {
            int r = f >> 4, c4 = (f & 15) << 2;
            float4 v = *(const float4*)(sa + (size_t)r*64 + c4);
            ushort4 h4, l4;
            h4.x = f2bf(v.x); l4.x = f2bf(v.x - bf2f(h4.x));
            h4.y = f2bf(v.y); l4.y = f2bf(v.y - bf2f(h4.y));
            h4.z = f2bf(v.z); l4.z = f2bf(v.z - bf2f(h4.z));
            h4.w = f2bf(v.w); l4.w = f2bf(v.w - bf2f(h4.w));
            *(ushort4*)(sInH + r*104 + c4) = h4;
            *(ushort4*)(sInL + r*104 + c4) = l4;
        }
        {
            int r = t >> 3, c = t & 7;
            const float* aa = act_others + ((size_t)a*BTOT + b0 + r)*18;
#pragma unroll
            for (int e = 0; e < 3; ++e) {
                int cc = c*3 + e;
                if (cc < 18) {
                    float v = aa[cc];
                    unsigned short hh = f2bf(v);
                    sInH[r*104 + 64 + cc] = hh;
                    sInL[r*104 + 64 + cc] = f2bf(v - bf2f(hh));
                }
            }
        }
        __syncthreads();

        // ---- enc = relu(inp @ We_a + be_a), split 3-term, wave slice 32 cols
        {
            f32x4 eacc[2][2] = {};
#pragma unroll
            for (int kt = 0; kt < 3; ++kt) {
                bhalf8 ah0 = *(const bhalf8*)(sInH + m*104      + kt*32 + qd*8);
                bhalf8 ah1 = *(const bhalf8*)(sInH + (16+m)*104 + kt*32 + qd*8);
                bhalf8 al0 = *(const bhalf8*)(sInL + m*104      + kt*32 + qd*8);
                bhalf8 al1 = *(const bhalf8*)(sInL + (16+m)*104 + kt*32 + qd*8);
#pragma unroll
                for (int nt2 = 0; nt2 < 2; ++nt2) {
                    int nt = 2*w + nt2;
                    const unsigned short* bp =
                        Wef2 + (size_t)a*24576 + ((nt*3 + kt)*64 + l)*16;
                    bhalf8 bh = *(const bhalf8*)(bp);
                    bhalf8 bl = *(const bhalf8*)(bp + 8);
                    eacc[0][nt2] = __builtin_amdgcn_mfma_f32_16x16x32_bf16(ah0, bh, eacc[0][nt2], 0, 0, 0);
                    eacc[1][nt2] = __builtin_amdgcn_mfma_f32_16x16x32_bf16(ah1, bh, eacc[1][nt2], 0, 0, 0);
                    eacc[0][nt2] = __builtin_amdgcn_mfma_f32_16x16x32_bf16(ah0, bl, eacc[0][nt2], 0, 0, 0);
                    eacc[1][nt2] = __builtin_amdgcn_mfma_f32_16x16x32_bf16(ah1, bl, eacc[1][nt2], 0, 0, 0);
                    eacc[0][nt2] = __builtin_amdgcn_mfma_f32_16x16x32_bf16(al0, bh, eacc[0][nt2], 0, 0, 0);
                    eacc[1][nt2] = __builtin_amdgcn_mfma_f32_16x16x32_bf16(al1, bh, eacc[1][nt2], 0, 0, 0);
                }
            }
            float be0 = be[a*128 + 32*w + m];
            float be1 = be[a*128 + 32*w + 16 + m];
#pragma unroll
            for (int rt = 0; rt < 2; ++rt)
#pragma unroll
                for (int nt2 = 0; nt2 < 2; ++nt2) {
                    float bb = nt2 ? be1 : be0;
#pragma unroll
                    for (int r = 0; r < 4; ++r) {
                        float e = fmaxf(eacc[rt][nt2][r] + bb, 0.f);
                        int row = rt*16 + qd*4 + r;
                        int col = 32*w + nt2*16 + m;
                        unsigned short hh = f2bf(e);
                        sEnH[row*136 + col] = hh;
                        sEnL[row*136 + col] = f2bf(e - bf2f(hh));
                        sEf [row*132 + col] = e;      // f32 copy for logits
                    }
                }
        }
        __syncthreads();

        // ---- logits (f32 enc × bf16 t) + online-softmax stats ----
        {
            const float4* ep4 = (const float4*)(sEf + b_l*132 + half*64);
            float part = 0.f;
#pragma unroll
            for (int i = 0; i < 8; ++i) {
                float4 e0 = ep4[2*i];
                float4 e1 = ep4[2*i+1];
                uint4 tt = tq[i];
                part += e0.x*bflo(tt.x) + e0.y*bfhi(tt.x)
                      + e0.z*bflo(tt.y) + e0.w*bfhi(tt.y);
                part += e1.x*bflo(tt.z) + e1.y*bfhi(tt.z)
                      + e1.z*bflo(tt.w) + e1.w*bfhi(tt.w);
            }
            part += __shfl_xor(part, 32);
            if (half == 0) {
                float lg = part * 0.17677669529663687f;   // 1/sqrt(32)
                int idx  = b_l*4 + w;
                float mo = sMv[idx];
                float mn = fmaxf(mo, lg);
                float al = __expf(mo - mn);
                float p  = __expf(lg - mn);
                sSv[idx] = sSv[idx]*al + p;
                sMv[idx] = mn;
                sAv[idx] = al;
                sPv[idx] = p;
            }
        }
        // stats produced and consumed by the same wave -> no barrier needed

        // ---- vals = relu(enc @ Wv + bv), split 3-term; online accumulate ----
        {
            f32x4 vacc[2][2] = {};
#pragma unroll
            for (int kt = 0; kt < 4; ++kt) {
                bhalf8 ah0 = *(const bhalf8*)(sEnH + m*136      + kt*32 + qd*8);
                bhalf8 ah1 = *(const bhalf8*)(sEnH + (16+m)*136 + kt*32 + qd*8);
                bhalf8 al0 = *(const bhalf8*)(sEnL + m*136      + kt*32 + qd*8);
                bhalf8 al1 = *(const bhalf8*)(sEnL + (16+m)*136 + kt*32 + qd*8);
#pragma unroll
                for (int nt2 = 0; nt2 < 2; ++nt2) {
                    int nt = 2*w + nt2;
                    const unsigned short* bp = Wvf2 + ((nt*4 + kt)*64 + l)*16;
                    bhalf8 bh = *(const bhalf8*)(bp);
                    bhalf8 bl = *(const bhalf8*)(bp + 8);
                    vacc[0][nt2] = __builtin_amdgcn_mfma_f32_16x16x32_bf16(ah0, bh, vacc[0][nt2], 0, 0, 0);
                    vacc[1][nt2] = __builtin_amdgcn_mfma_f32_16x16x32_bf16(ah1, bh, vacc[1][nt2], 0, 0, 0);
                    vacc[0][nt2] = __builtin_amdgcn_mfma_f32_16x16x32_bf16(ah0, bl, vacc[0][nt2], 0, 0, 0);
                    vacc[1][nt2] = __builtin_amdgcn_mfma_f32_16x16x32_bf16(ah1, bl, vacc[1][nt2], 0, 0, 0);
                    vacc[0][nt2] = __builtin_amdgcn_mfma_f32_16x16x32_bf16(al0, bh, vacc[0][nt2], 0, 0, 0);
                    vacc[1][nt2] = __builtin_amdgcn_mfma_f32_16x16x32_bf16(al1, bh, vacc[1][nt2], 0, 0, 0);
                }
            }
#pragma unroll
            for (int rt = 0; rt < 2; ++rt)
#pragma unroll
                for (int r = 0; r < 4; ++r) {
                    int row = rt*16 + qd*4 + r;
                    float al = sAv[row*4 + w];
                    float p  = sPv[row*4 + w];
#pragma unroll
                    for (int nt2 = 0; nt2 < 2; ++nt2) {
                        float bb = nt2 ? bv1 : bv0;
                        o4[rt][nt2][r] = o4[rt][nt2][r]*al
                                       + p*fmaxf(vacc[rt][nt2][r] + bb, 0.f);
                    }
                }
        }
    }
    __syncthreads();   // all sEn/sEf reads done; sOv overwrites union region

    // ---- normalize and dump ov to sOv f32 (stride 132) ----
#pragma unroll
    for (int rt = 0; rt < 2; ++rt)
#pragma unroll
        for (int r = 0; r < 4; ++r) {
            int row = rt*16 + qd*4 + r;
            float inv = 1.0f / sSv[row*4 + w];
#pragma unroll
            for (int nt2 = 0; nt2 < 2; ++nt2)
                sOv[row*132 + 32*w + nt2*16 + m] = o4[rt][nt2][r]*inv;
        }
    __syncthreads();

    // ---- final: x3o = ov @ w3_others (f32); out = relu(x3s+x3o).Wout + bout
    {
        float acc[2][4] = {};
#pragma unroll 4
        for (int k = 0; k < 128; ++k) {
            float4 w4 = *(const float4*)(w3_others + k*64 + c0);
            float a0 = sOv[(rg*2+0)*132 + k];
            float a1 = sOv[(rg*2+1)*132 + k];
            acc[0][0] += a0*w4.x; acc[0][1] += a0*w4.y; acc[0][2] += a0*w4.z; acc[0][3] += a0*w4.w;
            acc[1][0] += a1*w4.x; acc[1][1] += a1*w4.y; acc[1][2] += a1*w4.z; acc[1][3] += a1*w4.w;
        }
        float4 wo = *(const float4*)(Wout + c0);
        float bo = bout[0];
#pragma unroll
        for (int i = 0; i < 2; ++i) {
            float p = fmaxf(acc[i][0] + x3s[i][0], 0.f) * wo.x
                    + fmaxf(acc[i][1] + x3s[i][1], 0.f) * wo.y
                    + fmaxf(acc[i][2] + x3s[i][2], 0.f) * wo.z
                    + fmaxf(acc[i][3] + x3s[i][3], 0.f) * wo.w;
#pragma unroll
            for (int off = 1; off < 16; off <<= 1)
                p += __shfl_xor(p, off);
            if (cg == 0) out[b0 + rg*2 + i] = p + bo;
        }
    }
}

extern "C" void kernel_launch(void* const* d_in, const int* in_sizes, int n_in,
                              void* d_out, int out_size, void* d_ws, size_t ws_size,
                              hipStream_t stream) {
    (void)in_sizes; (void)n_in; (void)out_size; (void)ws_size;
    const float* state_one    = (const float*)d_in[0];
    const float* act_one      = (const float*)d_in[1];
    const float* state_others = (const float*)d_in[2];
    const float* act_others   = (const float*)d_in[3];
    const float* W1           = (const float*)d_in[4];
    const float* b1           = (const float*)d_in[5];
    const float* W2           = (const float*)d_in[6];
    const float* b2           = (const float*)d_in[7];
    const float* w3_self      = (const float*)d_in[8];
    const float* We           = (const float*)d_in[9];
    const float* be           = (const float*)d_in[10];
    const float* Wk           = (const float*)d_in[11];
    const float* Wq           = (const float*)d_in[12];
    const float* Wv           = (const float*)d_in[13];
    const float* bv           = (const float*)d_in[14];
    const float* w3_others    = (const float*)d_in[15];
    const float* Wout         = (const float*)d_in[16];
    const float* bout         = (const float*)d_in[17];
    float* out = (float*)d_out;

    unsigned short* Mf2  = (unsigned short*)d_ws;                    // 131072 B
    unsigned short* Wef2 = (unsigned short*)((char*)d_ws + 131072);  // 344064 B
    unsigned short* Wvf2 = (unsigned short*)((char*)d_ws + 475136);  // 65536 B

    fold_M_frag<<<128, 256, 0, stream>>>(Wk, Wq, Mf2);
    conv_We<<<336, 256, 0, stream>>>(We, Wef2);
    conv_Wv<<<64, 256, 0, stream>>>(Wv, Wvf2);
    fused_critic<<<BTOT/TB, 256, 0, stream>>>(
        state_one, act_one, state_others, act_others,
        W1, b1, W2, b2, w3_self, be, bv, w3_others, Wout, bout,
        Mf2, Wef2, Wvf2, out);
}

// Round 7
// 276.247 us; speedup vs baseline: 1.8982x; 1.6554x over previous
//
#include <hip/hip_runtime.h>
#include <hip/hip_bf16.h>

#define BTOT 32768
#define TB 32

typedef __attribute__((ext_vector_type(8))) short bhalf8;   // 8 bf16 = 4 VGPRs
typedef __attribute__((ext_vector_type(4))) float f32x4;    // MFMA acc

static __device__ __forceinline__ unsigned short f2bf(float x) {
    unsigned int u = __float_as_uint(x);
    u = (u + 0x7fffu + ((u >> 16) & 1u)) >> 16;
    return (unsigned short)u;
}
static __device__ __forceinline__ float bf2f(unsigned short s) {
    return __uint_as_float(((unsigned int)s) << 16);
}
static __device__ __forceinline__ float bflo(unsigned int u) {
    return __uint_as_float(u << 16);
}
static __device__ __forceinline__ float bfhi(unsigned int u) {
    return __uint_as_float(u & 0xffff0000u);
}

// ---------------------------------------------------------------------------
// Weight preprocessing into MFMA B-fragment-linear SPLIT bf16 (hi|lo).
// B-frag for (kt, nt): lane l holds B[k=kt*32+(l>>4)*8+j][n=nt*16+(l&15)],
// hi at idx = ((nt*KT+kt)*64 + l)*16 + j, lo at +8+j.
// ws: Mf2  @0       131072 B (M = Wq@Wk^T as [64 x 512], KT=2, NT=32)
//     Wef2 @131072  344064 B (per agent We[96 x 128], KT=3, NT=8)
//     Wvf2 @475136  65536 B  (Wv as [128 x 128], n=h*32+d, KT=4, NT=8)
// NOTE: kept as round 4's three separate kernels — that exact binary passed
// both correctness checks deterministically; rounds 5/6's restructures
// introduced an unexplained race. Do not "clean this up" without re-proving
// determinism.
// ---------------------------------------------------------------------------
__global__ __launch_bounds__(256) void fold_M_frag(
        const float* __restrict__ Wk, const float* __restrict__ Wq,
        unsigned short* __restrict__ Mf2)
{
    int tid = blockIdx.x * 256 + threadIdx.x;   // 32768
    int h  = tid >> 13;
    int jq = (tid >> 7) & 63;
    int j  = tid & 127;
    const float* q = Wq + (h*64 + jq)*32;
    const float* k = Wk + (h*128 + j)*32;
    float acc = 0.f;
#pragma unroll
    for (int d = 0; d < 32; d += 4) {
        float4 a = *(const float4*)(q + d);
        float4 b = *(const float4*)(k + d);
        acc += a.x*b.x + a.y*b.y + a.z*b.z + a.w*b.w;
    }
    unsigned short hi = f2bf(acc);
    unsigned short lo = f2bf(acc - bf2f(hi));
    int n  = h*128 + j;
    int kt = jq >> 5, qd = (jq >> 3) & 3, jj = jq & 7;
    int nt = n >> 4,  ln = n & 15;
    size_t base = (((nt*2 + kt)*64) + qd*16 + ln)*16;
    Mf2[base + jj]     = hi;
    Mf2[base + 8 + jj] = lo;
}

__global__ __launch_bounds__(256) void conv_We(
        const float* __restrict__ We, unsigned short* __restrict__ Wef2)
{
    int tid = blockIdx.x * 256 + threadIdx.x;   // 7*96*128 = 86016
    int a = tid / 12288;
    int r = tid - a*12288;
    int k = r >> 7;          // 0..95
    int n = r & 127;
    float v = (k < 82) ? We[((size_t)a*82 + k)*128 + n] : 0.f;
    unsigned short hi = f2bf(v);
    unsigned short lo = f2bf(v - bf2f(hi));
    int kt = k >> 5, qd = (k >> 3) & 3, j = k & 7;
    int nt = n >> 4, ln = n & 15;
    size_t base = (size_t)a*24576 + (((nt*3 + kt)*64) + qd*16 + ln)*16;
    Wef2[base + j]     = hi;
    Wef2[base + 8 + j] = lo;
}

__global__ __launch_bounds__(256) void conv_Wv(
        const float* __restrict__ Wv, unsigned short* __restrict__ Wvf2)
{
    int tid = blockIdx.x * 256 + threadIdx.x;   // 4*128*32 = 16384
    int h = tid >> 12;
    int j = (tid >> 5) & 127;
    int d = tid & 31;
    float v = Wv[tid];
    unsigned short hi = f2bf(v);
    unsigned short lo = f2bf(v - bf2f(hi));
    int k = j, n = h*32 + d;
    int kt = k >> 5, qd = (k >> 3) & 3, jj = k & 7;
    int nt = n >> 4, ln = n & 15;
    size_t base = (((nt*4 + kt)*64) + qd*16 + ln)*16;
    Wvf2[base + jj]     = hi;
    Wvf2[base + 8 + jj] = lo;
}

// ---------------------------------------------------------------------------
// Fused critic. TB=32 rows/block, 256 threads (4 waves), 1024 blocks.
// BYTE-FOR-BYTE round 4 (passed deterministically at 1 ULP) except
// __launch_bounds__ waves/EU 3 -> 2: 256-VGPR budget eliminates the scratch
// spills that produced 77 MB WRITE_SIZE / 145 MB spill re-reads and made
// round 4 HBM-bound at 352 us. 2 blocks/CU (8 waves/CU) is sufficient —
// spill traffic, not occupancy, was the binding constraint.
// LDS 49664 B:
//   self : sX f32[32x84]@0, sX1 f32[32x68]@10752, sX2 f32[32x68]@19456,
//          sX1bH bf16[32x72]@28160, sX1bL @32768
//   t    : sT bf16[32x520]@0 (freed after tq reg load)
//   agent: sInH bf16[32x104]@0, sInL @6656, sEnH bf16[32x136]@13312,
//          sEnL @22016, sEf f32[32x132]@30720
//   final: sOv f32[32x132]@0
//   stats @47616: m/s/alpha/p, each 32x4 f32
// ---------------------------------------------------------------------------
__global__ __launch_bounds__(256, 2) void fused_critic(
    const float* __restrict__ state_one, const float* __restrict__ act_one,
    const float* __restrict__ state_others, const float* __restrict__ act_others,
    const float* __restrict__ W1, const float* __restrict__ b1,
    const float* __restrict__ W2, const float* __restrict__ b2,
    const float* __restrict__ w3_self, const float* __restrict__ be,
    const float* __restrict__ bvp, const float* __restrict__ w3_others,
    const float* __restrict__ Wout, const float* __restrict__ bout,
    const unsigned short* __restrict__ Mf2, const unsigned short* __restrict__ Wef2,
    const unsigned short* __restrict__ Wvf2, float* __restrict__ out)
{
    __shared__ __align__(16) unsigned char smem[49664];
    float*          sX    = (float*)smem;                    // stride 84
    float*          sX1   = (float*)(smem + 10752);          // stride 68
    float*          sX2   = (float*)(smem + 19456);          // stride 68
    unsigned short* sX1bH = (unsigned short*)(smem + 28160); // stride 72
    unsigned short* sX1bL = (unsigned short*)(smem + 32768); // stride 72
    unsigned short* sT    = (unsigned short*)smem;           // stride 520
    unsigned short* sInH  = (unsigned short*)smem;           // stride 104
    unsigned short* sInL  = (unsigned short*)(smem + 6656);  // stride 104
    unsigned short* sEnH  = (unsigned short*)(smem + 13312); // stride 136
    unsigned short* sEnL  = (unsigned short*)(smem + 22016); // stride 136
    float*          sEf   = (float*)(smem + 30720);          // stride 132
    float*          sOv   = (float*)smem;                    // stride 132
    float*          sMv   = (float*)(smem + 47616);
    float*          sSv   = sMv + 128;
    float*          sAv   = sMv + 256;
    float*          sPv   = sMv + 384;

    const int t  = threadIdx.x;
    const int b0 = blockIdx.x * TB;
    const int w  = t >> 6;        // wave = head
    const int l  = t & 63;
    const int m  = l & 15;        // MFMA A row / C col
    const int qd = l >> 4;        // quad

    // ---- stage self input [32 x 78] f32 ----
    for (int f = t; f < TB*16; f += 256) {
        int r = f >> 4, c4 = (f & 15) << 2;
        *(float4*)(sX + r*84 + c4) =
            *(const float4*)(state_one + (size_t)(b0 + r)*64 + c4);
    }
    for (int f = t; f < TB*14; f += 256) {
        int r = f / 14, c = f - r*14;
        sX[r*84 + 64 + c] = act_one[(size_t)(b0 + r)*14 + c];
    }
    if (t < 128) { sMv[t] = -1e30f; sSv[t] = 0.f; }
    __syncthreads();

    const int cg = t & 15, rg = t >> 4;   // self/final map: 2 rows x 4 cols
    const int c0 = cg << 2;

    // ---- phase 1: x1 = relu(x @ W1 + b1) -> sX1 f32 + split bf16 ----
    {
        float acc[2][4] = {};
#pragma unroll 2
        for (int k = 0; k < 78; ++k) {
            float4 wv = *(const float4*)(W1 + k*64 + c0);
            float a0 = sX[(rg*2+0)*84 + k];
            float a1 = sX[(rg*2+1)*84 + k];
            acc[0][0] += a0*wv.x; acc[0][1] += a0*wv.y; acc[0][2] += a0*wv.z; acc[0][3] += a0*wv.w;
            acc[1][0] += a1*wv.x; acc[1][1] += a1*wv.y; acc[1][2] += a1*wv.z; acc[1][3] += a1*wv.w;
        }
        float4 bb = *(const float4*)(b1 + c0);
#pragma unroll
        for (int i = 0; i < 2; ++i) {
            int r = rg*2 + i;
            float v[4];
            v[0] = fmaxf(acc[i][0] + bb.x, 0.f);
            v[1] = fmaxf(acc[i][1] + bb.y, 0.f);
            v[2] = fmaxf(acc[i][2] + bb.z, 0.f);
            v[3] = fmaxf(acc[i][3] + bb.w, 0.f);
#pragma unroll
            for (int e = 0; e < 4; ++e) {
                sX1[r*68 + c0+e] = v[e];
                unsigned short hh = f2bf(v[e]);
                sX1bH[r*72 + c0+e] = hh;
                sX1bL[r*72 + c0+e] = f2bf(v[e] - bf2f(hh));
            }
        }
    }
    __syncthreads();

    // ---- phase 2: x2 = relu(x1 @ W2 + b2) -> sX2 f32 ----
    {
        float acc[2][4] = {};
#pragma unroll 4
        for (int k = 0; k < 64; ++k) {
            float4 wv = *(const float4*)(W2 + k*64 + c0);
            float a0 = sX1[(rg*2+0)*68 + k];
            float a1 = sX1[(rg*2+1)*68 + k];
            acc[0][0] += a0*wv.x; acc[0][1] += a0*wv.y; acc[0][2] += a0*wv.z; acc[0][3] += a0*wv.w;
            acc[1][0] += a1*wv.x; acc[1][1] += a1*wv.y; acc[1][2] += a1*wv.z; acc[1][3] += a1*wv.w;
        }
        float4 bb = *(const float4*)(b2 + c0);
#pragma unroll
        for (int i = 0; i < 2; ++i) {
            int r = rg*2 + i;
            sX2[r*68 + c0+0] = fmaxf(acc[i][0] + bb.x, 0.f);
            sX2[r*68 + c0+1] = fmaxf(acc[i][1] + bb.y, 0.f);
            sX2[r*68 + c0+2] = fmaxf(acc[i][2] + bb.z, 0.f);
            sX2[r*68 + c0+3] = fmaxf(acc[i][3] + bb.w, 0.f);
        }
    }
    __syncthreads();

    // ---- phase 3: x3_self fragment in registers (final-phase map) ----
    float x3s[2][4] = {};
    {
#pragma unroll 4
        for (int k = 0; k < 64; ++k) {
            float4 wv = *(const float4*)(w3_self + k*64 + c0);
            float a0 = sX2[(rg*2+0)*68 + k];
            float a1 = sX2[(rg*2+1)*68 + k];
            x3s[0][0] += a0*wv.x; x3s[0][1] += a0*wv.y; x3s[0][2] += a0*wv.z; x3s[0][3] += a0*wv.w;
            x3s[1][0] += a1*wv.x; x3s[1][1] += a1*wv.y; x3s[1][2] += a1*wv.z; x3s[1][3] += a1*wv.w;
        }
    }

    // ---- phase 4: t = x1 @ M, split 3-term MFMA (~f32), -> sT bf16 ----
    {
        f32x4 tacc[2][8] = {};
#pragma unroll
        for (int kt = 0; kt < 2; ++kt) {
            bhalf8 ah0 = *(const bhalf8*)(sX1bH + m*72      + kt*32 + qd*8);
            bhalf8 ah1 = *(const bhalf8*)(sX1bH + (16+m)*72 + kt*32 + qd*8);
            bhalf8 al0 = *(const bhalf8*)(sX1bL + m*72      + kt*32 + qd*8);
            bhalf8 al1 = *(const bhalf8*)(sX1bL + (16+m)*72 + kt*32 + qd*8);
#pragma unroll
            for (int nt2 = 0; nt2 < 8; ++nt2) {
                int nt = w*8 + nt2;
                const unsigned short* bp = Mf2 + ((nt*2 + kt)*64 + l)*16;
                bhalf8 bh = *(const bhalf8*)(bp);
                bhalf8 bl = *(const bhalf8*)(bp + 8);
                tacc[0][nt2] = __builtin_amdgcn_mfma_f32_16x16x32_bf16(ah0, bh, tacc[0][nt2], 0, 0, 0);
                tacc[1][nt2] = __builtin_amdgcn_mfma_f32_16x16x32_bf16(ah1, bh, tacc[1][nt2], 0, 0, 0);
                tacc[0][nt2] = __builtin_amdgcn_mfma_f32_16x16x32_bf16(ah0, bl, tacc[0][nt2], 0, 0, 0);
                tacc[1][nt2] = __builtin_amdgcn_mfma_f32_16x16x32_bf16(ah1, bl, tacc[1][nt2], 0, 0, 0);
                tacc[0][nt2] = __builtin_amdgcn_mfma_f32_16x16x32_bf16(al0, bh, tacc[0][nt2], 0, 0, 0);
                tacc[1][nt2] = __builtin_amdgcn_mfma_f32_16x16x32_bf16(al1, bh, tacc[1][nt2], 0, 0, 0);
            }
        }
        __syncthreads();   // all reads of sX1b*/sX2 done before sT overwrite
#pragma unroll
        for (int rt = 0; rt < 2; ++rt)
#pragma unroll
            for (int nt2 = 0; nt2 < 8; ++nt2)
#pragma unroll
                for (int r = 0; r < 4; ++r)
                    sT[(rt*16 + qd*4 + r)*520 + w*128 + nt2*16 + m] =
                        f2bf(tacc[rt][nt2][r]);
    }
    __syncthreads();

    // ---- load this thread's t-slice into registers ----
    const int b_l = l & 31, half = l >> 5;
    uint4 tq[8];
    {
        const uint4* tp4 = (const uint4*)(sT + b_l*520 + w*128 + half*64);
#pragma unroll
        for (int i = 0; i < 8; ++i) tq[i] = tp4[i];
    }
    __syncthreads();   // sT region free for sInH/sInL

    // zero-pad sIn cols 80..95 once (staging rewrites 0..81 each agent)
    for (int f = t; f < TB*16; f += 256) {
        int r = f >> 4, c = f & 15;
        sInH[r*104 + 80 + c] = 0;
        sInL[r*104 + 80 + c] = 0;
    }

    const float bv0 = bvp[w*32 + m];
    const float bv1 = bvp[w*32 + 16 + m];
    f32x4 o4[2][2] = {};

    for (int a = 0; a < 7; ++a) {
        __syncthreads();
        // ---- stage other-agent input f32 -> split bf16 LDS ----
        const float* sa = state_others + ((size_t)a*BTOT + b0)*64;
        for (int f = t; f < TB*16; f += 256) {
            int r = f >> 4, c4 = (f & 15) << 2;
            float4 v = *(const float4*)(sa + (size_t)r*64 + c4);
            ushort4 h4, l4;
            h4.x = f2bf(v.x); l4.x = f2bf(v.x - bf2f(h4.x));
            h4.y = f2bf(v.y); l4.y = f2bf(v.y - bf2f(h4.y));
            h4.z = f2bf(v.z); l4.z = f2bf(v.z - bf2f(h4.z));
            h4.w = f2bf(v.w); l4.w = f2bf(v.w - bf2f(h4.w));
            *(ushort4*)(sInH + r*104 + c4) = h4;
            *(ushort4*)(sInL + r*104 + c4) = l4;
        }
        {
            int r = t >> 3, c = t & 7;
            const float* aa = act_others + ((size_t)a*BTOT + b0 + r)*18;
#pragma unroll
            for (int e = 0; e < 3; ++e) {
                int cc = c*3 + e;
                if (cc < 18) {
                    float v = aa[cc];
                    unsigned short hh = f2bf(v);
                    sInH[r*104 + 64 + cc] = hh;
                    sInL[r*104 + 64 + cc] = f2bf(v - bf2f(hh));
                }
            }
        }
        __syncthreads();

        // ---- enc = relu(inp @ We_a + be_a), split 3-term, wave slice 32 cols
        {
            f32x4 eacc[2][2] = {};
#pragma unroll
            for (int kt = 0; kt < 3; ++kt) {
                bhalf8 ah0 = *(const bhalf8*)(sInH + m*104      + kt*32 + qd*8);
                bhalf8 ah1 = *(const bhalf8*)(sInH + (16+m)*104 + kt*32 + qd*8);
                bhalf8 al0 = *(const bhalf8*)(sInL + m*104      + kt*32 + qd*8);
                bhalf8 al1 = *(const bhalf8*)(sInL + (16+m)*104 + kt*32 + qd*8);
#pragma unroll
                for (int nt2 = 0; nt2 < 2; ++nt2) {
                    int nt = 2*w + nt2;
                    const unsigned short* bp =
                        Wef2 + (size_t)a*24576 + ((nt*3 + kt)*64 + l)*16;
                    bhalf8 bh = *(const bhalf8*)(bp);
                    bhalf8 bl = *(const bhalf8*)(bp + 8);
                    eacc[0][nt2] = __builtin_amdgcn_mfma_f32_16x16x32_bf16(ah0, bh, eacc[0][nt2], 0, 0, 0);
                    eacc[1][nt2] = __builtin_amdgcn_mfma_f32_16x16x32_bf16(ah1, bh, eacc[1][nt2], 0, 0, 0);
                    eacc[0][nt2] = __builtin_amdgcn_mfma_f32_16x16x32_bf16(ah0, bl, eacc[0][nt2], 0, 0, 0);
                    eacc[1][nt2] = __builtin_amdgcn_mfma_f32_16x16x32_bf16(ah1, bl, eacc[1][nt2], 0, 0, 0);
                    eacc[0][nt2] = __builtin_amdgcn_mfma_f32_16x16x32_bf16(al0, bh, eacc[0][nt2], 0, 0, 0);
                    eacc[1][nt2] = __builtin_amdgcn_mfma_f32_16x16x32_bf16(al1, bh, eacc[1][nt2], 0, 0, 0);
                }
            }
            float be0 = be[a*128 + 32*w + m];
            float be1 = be[a*128 + 32*w + 16 + m];
#pragma unroll
            for (int rt = 0; rt < 2; ++rt)
#pragma unroll
                for (int nt2 = 0; nt2 < 2; ++nt2) {
                    float bb = nt2 ? be1 : be0;
#pragma unroll
                    for (int r = 0; r < 4; ++r) {
                        float e = fmaxf(eacc[rt][nt2][r] + bb, 0.f);
                        int row = rt*16 + qd*4 + r;
                        int col = 32*w + nt2*16 + m;
                        unsigned short hh = f2bf(e);
                        sEnH[row*136 + col] = hh;
                        sEnL[row*136 + col] = f2bf(e - bf2f(hh));
                        sEf [row*132 + col] = e;      // f32 copy for logits
                    }
                }
        }
        __syncthreads();

        // ---- logits (f32 enc x bf16 t) + online-softmax stats ----
        {
            const float4* ep4 = (const float4*)(sEf + b_l*132 + half*64);
            float part = 0.f;
#pragma unroll
            for (int i = 0; i < 8; ++i) {
                float4 e0 = ep4[2*i];
                float4 e1 = ep4[2*i+1];
                uint4 tt = tq[i];
                part += e0.x*bflo(tt.x) + e0.y*bfhi(tt.x)
                      + e0.z*bflo(tt.y) + e0.w*bfhi(tt.y);
                part += e1.x*bflo(tt.z) + e1.y*bfhi(tt.z)
                      + e1.z*bflo(tt.w) + e1.w*bfhi(tt.w);
            }
            part += __shfl_xor(part, 32);
            if (half == 0) {
                float lg = part * 0.17677669529663687f;   // 1/sqrt(32)
                int idx  = b_l*4 + w;
                float mo = sMv[idx];
                float mn = fmaxf(mo, lg);
                float al = __expf(mo - mn);
                float p  = __expf(lg - mn);
                sSv[idx] = sSv[idx]*al + p;
                sMv[idx] = mn;
                sAv[idx] = al;
                sPv[idx] = p;
            }
        }
        // stats produced and consumed by the same wave -> no barrier needed

        // ---- vals = relu(enc @ Wv + bv), split 3-term; online accumulate ----
        {
            f32x4 vacc[2][2] = {};
#pragma unroll
            for (int kt = 0; kt < 4; ++kt) {
                bhalf8 ah0 = *(const bhalf8*)(sEnH + m*136      + kt*32 + qd*8);
                bhalf8 ah1 = *(const bhalf8*)(sEnH + (16+m)*136 + kt*32 + qd*8);
                bhalf8 al0 = *(const bhalf8*)(sEnL + m*136      + kt*32 + qd*8);
                bhalf8 al1 = *(const bhalf8*)(sEnL + (16+m)*136 + kt*32 + qd*8);
#pragma unroll
                for (int nt2 = 0; nt2 < 2; ++nt2) {
                    int nt = 2*w + nt2;
                    const unsigned short* bp = Wvf2 + ((nt*4 + kt)*64 + l)*16;
                    bhalf8 bh = *(const bhalf8*)(bp);
                    bhalf8 bl = *(const bhalf8*)(bp + 8);
                    vacc[0][nt2] = __builtin_amdgcn_mfma_f32_16x16x32_bf16(ah0, bh, vacc[0][nt2], 0, 0, 0);
                    vacc[1][nt2] = __builtin_amdgcn_mfma_f32_16x16x32_bf16(ah1, bh, vacc[1][nt2], 0, 0, 0);
                    vacc[0][nt2] = __builtin_amdgcn_mfma_f32_16x16x32_bf16(ah0, bl, vacc[0][nt2], 0, 0, 0);
                    vacc[1][nt2] = __builtin_amdgcn_mfma_f32_16x16x32_bf16(ah1, bl, vacc[1][nt2], 0, 0, 0);
                    vacc[0][nt2] = __builtin_amdgcn_mfma_f32_16x16x32_bf16(al0, bh, vacc[0][nt2], 0, 0, 0);
                    vacc[1][nt2] = __builtin_amdgcn_mfma_f32_16x16x32_bf16(al1, bh, vacc[1][nt2], 0, 0, 0);
                }
            }
#pragma unroll
            for (int rt = 0; rt < 2; ++rt)
#pragma unroll
                for (int r = 0; r < 4; ++r) {
                    int row = rt*16 + qd*4 + r;
                    float al = sAv[row*4 + w];
                    float p  = sPv[row*4 + w];
#pragma unroll
                    for (int nt2 = 0; nt2 < 2; ++nt2) {
                        float bb = nt2 ? bv1 : bv0;
                        o4[rt][nt2][r] = o4[rt][nt2][r]*al
                                       + p*fmaxf(vacc[rt][nt2][r] + bb, 0.f);
                    }
                }
        }
    }
    __syncthreads();   // all sEn/sEf reads done; sOv overwrites union region

    // ---- normalize and dump ov to sOv f32 (stride 132) ----
#pragma unroll
    for (int rt = 0; rt < 2; ++rt)
#pragma unroll
        for (int r = 0; r < 4; ++r) {
            int row = rt*16 + qd*4 + r;
            float inv = 1.0f / sSv[row*4 + w];
#pragma unroll
            for (int nt2 = 0; nt2 < 2; ++nt2)
                sOv[row*132 + 32*w + nt2*16 + m] = o4[rt][nt2][r]*inv;
        }
    __syncthreads();

    // ---- final: x3o = ov @ w3_others (f32); out = relu(x3s+x3o).Wout + bout
    {
        float acc[2][4] = {};
#pragma unroll 4
        for (int k = 0; k < 128; ++k) {
            float4 w4 = *(const float4*)(w3_others + k*64 + c0);
            float a0 = sOv[(rg*2+0)*132 + k];
            float a1 = sOv[(rg*2+1)*132 + k];
            acc[0][0] += a0*w4.x; acc[0][1] += a0*w4.y; acc[0][2] += a0*w4.z; acc[0][3] += a0*w4.w;
            acc[1][0] += a1*w4.x; acc[1][1] += a1*w4.y; acc[1][2] += a1*w4.z; acc[1][3] += a1*w4.w;
        }
        float4 wo = *(const float4*)(Wout + c0);
        float bo = bout[0];
#pragma unroll
        for (int i = 0; i < 2; ++i) {
            float p = fmaxf(acc[i][0] + x3s[i][0], 0.f) * wo.x
                    + fmaxf(acc[i][1] + x3s[i][1], 0.f) * wo.y
                    + fmaxf(acc[i][2] + x3s[i][2], 0.f) * wo.z
                    + fmaxf(acc[i][3] + x3s[i][3], 0.f) * wo.w;
#pragma unroll
            for (int off = 1; off < 16; off <<= 1)
                p += __shfl_xor(p, off);
            if (cg == 0) out[b0 + rg*2 + i] = p + bo;
        }
    }
}

extern "C" void kernel_launch(void* const* d_in, const int* in_sizes, int n_in,
                              void* d_out, int out_size, void* d_ws, size_t ws_size,
                              hipStream_t stream) {
    (void)in_sizes; (void)n_in; (void)out_size; (void)ws_size;
    const float* state_one    = (const float*)d_in[0];
    const float* act_one      = (const float*)d_in[1];
    const float* state_others = (const float*)d_in[2];
    const float* act_others   = (const float*)d_in[3];
    const float* W1           = (const float*)d_in[4];
    const float* b1           = (const float*)d_in[5];
    const float* W2           = (const float*)d_in[6];
    const float* b2           = (const float*)d_in[7];
    const float* w3_self      = (const float*)d_in[8];
    const float* We           = (const float*)d_in[9];
    const float* be           = (const float*)d_in[10];
    const float* Wk           = (const float*)d_in[11];
    const float* Wq           = (const float*)d_in[12];
    const float* Wv           = (const float*)d_in[13];
    const float* bv           = (const float*)d_in[14];
    const float* w3_others    = (const float*)d_in[15];
    const float* Wout         = (const float*)d_in[16];
    const float* bout         = (const float*)d_in[17];
    float* out = (float*)d_out;

    unsigned short* Mf2  = (unsigned short*)d_ws;                    // 131072 B
    unsigned short* Wef2 = (unsigned short*)((char*)d_ws + 131072);  // 344064 B
    unsigned short* Wvf2 = (unsigned short*)((char*)d_ws + 475136);  // 65536 B

    fold_M_frag<<<128, 256, 0, stream>>>(Wk, Wq, Mf2);
    conv_We<<<336, 256, 0, stream>>>(We, Wef2);
    conv_Wv<<<64, 256, 0, stream>>>(Wv, Wvf2);
    fused_critic<<<BTOT/TB, 256, 0, stream>>>(
        state_one, act_one, state_others, act_others,
        W1, b1, W2, b2, w3_self, be, bv, w3_others, Wout, bout,
        Mf2, Wef2, Wvf2, out);
}

// Round 9
// 275.638 us; speedup vs baseline: 1.9024x; 1.0022x over previous
//
#include <hip/hip_runtime.h>
#include <hip/hip_bf16.h>

#define BTOT 32768
#define TB 32

typedef __attribute__((ext_vector_type(8))) short bhalf8;   // 8 bf16 = 4 VGPRs
typedef __attribute__((ext_vector_type(4))) float f32x4;    // MFMA acc

static __device__ __forceinline__ unsigned short f2bf(float x) {
    unsigned int u = __float_as_uint(x);
    u = (u + 0x7fffu + ((u >> 16) & 1u)) >> 16;
    return (unsigned short)u;
}
static __device__ __forceinline__ float bf2f(unsigned short s) {
    return __uint_as_float(((unsigned int)s) << 16);
}
static __device__ __forceinline__ float bflo(unsigned int u) {
    return __uint_as_float(u << 16);
}
static __device__ __forceinline__ float bfhi(unsigned int u) {
    return __uint_as_float(u & 0xffff0000u);
}

// ---------------------------------------------------------------------------
// Weight preprocessing into MFMA B-fragment-linear SPLIT bf16 (hi|lo).
// B-frag for (kt, nt): lane l holds B[k=kt*32+(l>>4)*8+j][n=nt*16+(l&15)],
// hi at idx = ((nt*KT+kt)*64 + l)*16 + j, lo at +8+j.
// ws: Mf2  @0       131072 B (M = Wq@Wk^T as [64 x 512], KT=2, NT=32)
//     Wef2 @131072  344064 B (per agent We[96 x 128], KT=3, NT=8)
//     Wvf2 @475136  65536 B  (Wv as [128 x 128], n=h*32+d, KT=4, NT=8)
// Quarantine note: rounds 5/6's fused preprocess + 2-pass t-phase correlated
// with nondeterminism; kept as three kernels + single-pass t-phase.
// ---------------------------------------------------------------------------
__global__ __launch_bounds__(256) void fold_M_frag(
        const float* __restrict__ Wk, const float* __restrict__ Wq,
        unsigned short* __restrict__ Mf2)
{
    int tid = blockIdx.x * 256 + threadIdx.x;   // 32768
    int h  = tid >> 13;
    int jq = (tid >> 7) & 63;
    int j  = tid & 127;
    const float* q = Wq + (h*64 + jq)*32;
    const float* k = Wk + (h*128 + j)*32;
    float acc = 0.f;
#pragma unroll
    for (int d = 0; d < 32; d += 4) {
        float4 a = *(const float4*)(q + d);
        float4 b = *(const float4*)(k + d);
        acc += a.x*b.x + a.y*b.y + a.z*b.z + a.w*b.w;
    }
    unsigned short hi = f2bf(acc);
    unsigned short lo = f2bf(acc - bf2f(hi));
    int n  = h*128 + j;
    int kt = jq >> 5, qd = (jq >> 3) & 3, jj = jq & 7;
    int nt = n >> 4,  ln = n & 15;
    size_t base = (((nt*2 + kt)*64) + qd*16 + ln)*16;
    Mf2[base + jj]     = hi;
    Mf2[base + 8 + jj] = lo;
}

__global__ __launch_bounds__(256) void conv_We(
        const float* __restrict__ We, unsigned short* __restrict__ Wef2)
{
    int tid = blockIdx.x * 256 + threadIdx.x;   // 7*96*128 = 86016
    int a = tid / 12288;
    int r = tid - a*12288;
    int k = r >> 7;          // 0..95
    int n = r & 127;
    float v = (k < 82) ? We[((size_t)a*82 + k)*128 + n] : 0.f;
    unsigned short hi = f2bf(v);
    unsigned short lo = f2bf(v - bf2f(hi));
    int kt = k >> 5, qd = (k >> 3) & 3, j = k & 7;
    int nt = n >> 4, ln = n & 15;
    size_t base = (size_t)a*24576 + (((nt*3 + kt)*64) + qd*16 + ln)*16;
    Wef2[base + j]     = hi;
    Wef2[base + 8 + j] = lo;
}

__global__ __launch_bounds__(256) void conv_Wv(
        const float* __restrict__ Wv, unsigned short* __restrict__ Wvf2)
{
    int tid = blockIdx.x * 256 + threadIdx.x;   // 4*128*32 = 16384
    int h = tid >> 12;
    int j = (tid >> 5) & 127;
    int d = tid & 31;
    float v = Wv[tid];
    unsigned short hi = f2bf(v);
    unsigned short lo = f2bf(v - bf2f(hi));
    int k = j, n = h*32 + d;
    int kt = k >> 5, qd = (k >> 3) & 3, jj = k & 7;
    int nt = n >> 4, ln = n & 15;
    size_t base = (((nt*4 + kt)*64) + qd*16 + ln)*16;
    Wvf2[base + jj]     = hi;
    Wvf2[base + 8 + jj] = lo;
}

// ---------------------------------------------------------------------------
// Fused critic. TB=32 rows/block, 256 threads (4 waves), 1024 blocks.
// = round 8 with the online-softmax stats moved from LDS into REGISTERS:
// the old "same-wave LDS write->read without barrier" pattern (sMv/sSv/
// sAv/sPv) was the only un-barriered LDS dataflow in the kernel, and all
// nondeterministic failures (R5/R6/R8) occurred exactly when occupancy
// exceeded 2 blocks/CU — consistent with DS-pipe reordering under
// contention. Now every lane redundantly computes m/s/alpha/p for its row
// (both halves hold bit-identical 'part' after shfl_xor(32); f32 add is
// commutative) and vals/normalize fetch alpha, p, 1/s via __shfl —
// no LDS, no ordering assumption. Every remaining LDS producer->consumer
// crosses a __syncthreads.
// LDS 37376 B -> 4 blocks/CU:
//   self : sX f32[32x84]@0, sX1 f32[32x68]@10752, sX2 f32[32x68]@19456,
//          sX1bH bf16[32x72]@28160, sX1bL @32768 (ends 37376)
//   t    : sT bf16[32x520]@0 (freed after tq reg load)
//   agent: sInH bf16[32x104]@0, sInL @6656, sEnH bf16[32x136]@13312,
//          sEnL @22016 (ends 30720)
//   final: sOv f32[32x132]@0
// ---------------------------------------------------------------------------
__global__ __launch_bounds__(256, 2) void fused_critic(
    const float* __restrict__ state_one, const float* __restrict__ act_one,
    const float* __restrict__ state_others, const float* __restrict__ act_others,
    const float* __restrict__ W1, const float* __restrict__ b1,
    const float* __restrict__ W2, const float* __restrict__ b2,
    const float* __restrict__ w3_self, const float* __restrict__ be,
    const float* __restrict__ bvp, const float* __restrict__ w3_others,
    const float* __restrict__ Wout, const float* __restrict__ bout,
    const unsigned short* __restrict__ Mf2, const unsigned short* __restrict__ Wef2,
    const unsigned short* __restrict__ Wvf2, float* __restrict__ out)
{
    __shared__ __align__(16) unsigned char smem[37376];
    float*          sX    = (float*)smem;                    // stride 84
    float*          sX1   = (float*)(smem + 10752);          // stride 68
    float*          sX2   = (float*)(smem + 19456);          // stride 68
    unsigned short* sX1bH = (unsigned short*)(smem + 28160); // stride 72
    unsigned short* sX1bL = (unsigned short*)(smem + 32768); // stride 72
    unsigned short* sT    = (unsigned short*)smem;           // stride 520
    unsigned short* sInH  = (unsigned short*)smem;           // stride 104
    unsigned short* sInL  = (unsigned short*)(smem + 6656);  // stride 104
    unsigned short* sEnH  = (unsigned short*)(smem + 13312); // stride 136
    unsigned short* sEnL  = (unsigned short*)(smem + 22016); // stride 136
    float*          sOv   = (float*)smem;                    // stride 132

    const int t  = threadIdx.x;
    const int b0 = blockIdx.x * TB;
    const int w  = t >> 6;        // wave = head
    const int l  = t & 63;
    const int m  = l & 15;        // MFMA A row / C col
    const int qd = l >> 4;        // quad

    // ---- stage self input [32 x 78] f32 ----
    for (int f = t; f < TB*16; f += 256) {
        int r = f >> 4, c4 = (f & 15) << 2;
        *(float4*)(sX + r*84 + c4) =
            *(const float4*)(state_one + (size_t)(b0 + r)*64 + c4);
    }
    for (int f = t; f < TB*14; f += 256) {
        int r = f / 14, c = f - r*14;
        sX[r*84 + 64 + c] = act_one[(size_t)(b0 + r)*14 + c];
    }
    __syncthreads();

    const int cg = t & 15, rg = t >> 4;   // self/final map: 2 rows x 4 cols
    const int c0 = cg << 2;

    // ---- phase 1: x1 = relu(x @ W1 + b1) -> sX1 f32 + split bf16 ----
    {
        float acc[2][4] = {};
#pragma unroll 2
        for (int k = 0; k < 78; ++k) {
            float4 wv = *(const float4*)(W1 + k*64 + c0);
            float a0 = sX[(rg*2+0)*84 + k];
            float a1 = sX[(rg*2+1)*84 + k];
            acc[0][0] += a0*wv.x; acc[0][1] += a0*wv.y; acc[0][2] += a0*wv.z; acc[0][3] += a0*wv.w;
            acc[1][0] += a1*wv.x; acc[1][1] += a1*wv.y; acc[1][2] += a1*wv.z; acc[1][3] += a1*wv.w;
        }
        float4 bb = *(const float4*)(b1 + c0);
#pragma unroll
        for (int i = 0; i < 2; ++i) {
            int r = rg*2 + i;
            float v[4];
            v[0] = fmaxf(acc[i][0] + bb.x, 0.f);
            v[1] = fmaxf(acc[i][1] + bb.y, 0.f);
            v[2] = fmaxf(acc[i][2] + bb.z, 0.f);
            v[3] = fmaxf(acc[i][3] + bb.w, 0.f);
#pragma unroll
            for (int e = 0; e < 4; ++e) {
                sX1[r*68 + c0+e] = v[e];
                unsigned short hh = f2bf(v[e]);
                sX1bH[r*72 + c0+e] = hh;
                sX1bL[r*72 + c0+e] = f2bf(v[e] - bf2f(hh));
            }
        }
    }
    __syncthreads();

    // ---- phase 2: x2 = relu(x1 @ W2 + b2) -> sX2 f32 ----
    {
        float acc[2][4] = {};
#pragma unroll 4
        for (int k = 0; k < 64; ++k) {
            float4 wv = *(const float4*)(W2 + k*64 + c0);
            float a0 = sX1[(rg*2+0)*68 + k];
            float a1 = sX1[(rg*2+1)*68 + k];
            acc[0][0] += a0*wv.x; acc[0][1] += a0*wv.y; acc[0][2] += a0*wv.z; acc[0][3] += a0*wv.w;
            acc[1][0] += a1*wv.x; acc[1][1] += a1*wv.y; acc[1][2] += a1*wv.z; acc[1][3] += a1*wv.w;
        }
        float4 bb = *(const float4*)(b2 + c0);
#pragma unroll
        for (int i = 0; i < 2; ++i) {
            int r = rg*2 + i;
            sX2[r*68 + c0+0] = fmaxf(acc[i][0] + bb.x, 0.f);
            sX2[r*68 + c0+1] = fmaxf(acc[i][1] + bb.y, 0.f);
            sX2[r*68 + c0+2] = fmaxf(acc[i][2] + bb.z, 0.f);
            sX2[r*68 + c0+3] = fmaxf(acc[i][3] + bb.w, 0.f);
        }
    }
    __syncthreads();

    // ---- phase 3: x3_self fragment in registers (final-phase map) ----
    float x3s[2][4] = {};
    {
#pragma unroll 4
        for (int k = 0; k < 64; ++k) {
            float4 wv = *(const float4*)(w3_self + k*64 + c0);
            float a0 = sX2[(rg*2+0)*68 + k];
            float a1 = sX2[(rg*2+1)*68 + k];
            x3s[0][0] += a0*wv.x; x3s[0][1] += a0*wv.y; x3s[0][2] += a0*wv.z; x3s[0][3] += a0*wv.w;
            x3s[1][0] += a1*wv.x; x3s[1][1] += a1*wv.y; x3s[1][2] += a1*wv.z; x3s[1][3] += a1*wv.w;
        }
    }

    // ---- phase 4: t = x1 @ M, split 3-term MFMA (~f32), -> sT bf16 ----
    {
        f32x4 tacc[2][8] = {};
#pragma unroll
        for (int kt = 0; kt < 2; ++kt) {
            bhalf8 ah0 = *(const bhalf8*)(sX1bH + m*72      + kt*32 + qd*8);
            bhalf8 ah1 = *(const bhalf8*)(sX1bH + (16+m)*72 + kt*32 + qd*8);
            bhalf8 al0 = *(const bhalf8*)(sX1bL + m*72      + kt*32 + qd*8);
            bhalf8 al1 = *(const bhalf8*)(sX1bL + (16+m)*72 + kt*32 + qd*8);
#pragma unroll
            for (int nt2 = 0; nt2 < 8; ++nt2) {
                int nt = w*8 + nt2;
                const unsigned short* bp = Mf2 + ((nt*2 + kt)*64 + l)*16;
                bhalf8 bh = *(const bhalf8*)(bp);
                bhalf8 bl = *(const bhalf8*)(bp + 8);
                tacc[0][nt2] = __builtin_amdgcn_mfma_f32_16x16x32_bf16(ah0, bh, tacc[0][nt2], 0, 0, 0);
                tacc[1][nt2] = __builtin_amdgcn_mfma_f32_16x16x32_bf16(ah1, bh, tacc[1][nt2], 0, 0, 0);
                tacc[0][nt2] = __builtin_amdgcn_mfma_f32_16x16x32_bf16(ah0, bl, tacc[0][nt2], 0, 0, 0);
                tacc[1][nt2] = __builtin_amdgcn_mfma_f32_16x16x32_bf16(ah1, bl, tacc[1][nt2], 0, 0, 0);
                tacc[0][nt2] = __builtin_amdgcn_mfma_f32_16x16x32_bf16(al0, bh, tacc[0][nt2], 0, 0, 0);
                tacc[1][nt2] = __builtin_amdgcn_mfma_f32_16x16x32_bf16(al1, bh, tacc[1][nt2], 0, 0, 0);
            }
        }
        __syncthreads();   // all reads of sX1b*/sX2 done before sT overwrite
#pragma unroll
        for (int rt = 0; rt < 2; ++rt)
#pragma unroll
            for (int nt2 = 0; nt2 < 8; ++nt2)
#pragma unroll
                for (int r = 0; r < 4; ++r)
                    sT[(rt*16 + qd*4 + r)*520 + w*128 + nt2*16 + m] =
                        f2bf(tacc[rt][nt2][r]);
    }
    __syncthreads();

    // ---- load this thread's t-slice into registers ----
    const int b_l = l & 31, half = l >> 5;
    uint4 tq[8];
    {
        const uint4* tp4 = (const uint4*)(sT + b_l*520 + w*128 + half*64);
#pragma unroll
        for (int i = 0; i < 8; ++i) tq[i] = tp4[i];
    }
    __syncthreads();   // sT region free for sInH/sInL

    // zero-pad sIn cols 80..95 once (staging rewrites 0..81 each agent)
    for (int f = t; f < TB*16; f += 256) {
        int r = f >> 4, c = f & 15;
        sInH[r*104 + 80 + c] = 0;
        sInL[r*104 + 80 + c] = 0;
    }

    const float bv0 = bvp[w*32 + m];
    const float bv1 = bvp[w*32 + 16 + m];
    f32x4 o4[2][2] = {};
    // online-softmax state for row b_l of head w, replicated in both halves
    float mR = -1e30f, sR = 0.f;

    for (int a = 0; a < 7; ++a) {
        __syncthreads();
        // ---- stage other-agent input f32 -> split bf16 LDS ----
        const float* sa = state_others + ((size_t)a*BTOT + b0)*64;
        for (int f = t; f < TB*16; f += 256) {
            int r = f >> 4, c4 = (f & 15) << 2;
            float4 v = *(const float4*)(sa + (size_t)r*64 + c4);
            ushort4 h4, l4;
            h4.x = f2bf(v.x); l4.x = f2bf(v.x - bf2f(h4.x));
            h4.y = f2bf(v.y); l4.y = f2bf(v.y - bf2f(h4.y));
            h4.z = f2bf(v.z); l4.z = f2bf(v.z - bf2f(h4.z));
            h4.w = f2bf(v.w); l4.w = f2bf(v.w - bf2f(h4.w));
            *(ushort4*)(sInH + r*104 + c4) = h4;
            *(ushort4*)(sInL + r*104 + c4) = l4;
        }
        {
            int r = t >> 3, c = t & 7;
            const float* aa = act_others + ((size_t)a*BTOT + b0 + r)*18;
#pragma unroll
            for (int e = 0; e < 3; ++e) {
                int cc = c*3 + e;
                if (cc < 18) {
                    float v = aa[cc];
                    unsigned short hh = f2bf(v);
                    sInH[r*104 + 64 + cc] = hh;
                    sInL[r*104 + 64 + cc] = f2bf(v - bf2f(hh));
                }
            }
        }
        __syncthreads();

        // ---- enc = relu(inp @ We_a + be_a), split 3-term, wave slice 32 cols
        {
            f32x4 eacc[2][2] = {};
#pragma unroll
            for (int kt = 0; kt < 3; ++kt) {
                bhalf8 ah0 = *(const bhalf8*)(sInH + m*104      + kt*32 + qd*8);
                bhalf8 ah1 = *(const bhalf8*)(sInH + (16+m)*104 + kt*32 + qd*8);
                bhalf8 al0 = *(const bhalf8*)(sInL + m*104      + kt*32 + qd*8);
                bhalf8 al1 = *(const bhalf8*)(sInL + (16+m)*104 + kt*32 + qd*8);
#pragma unroll
                for (int nt2 = 0; nt2 < 2; ++nt2) {
                    int nt = 2*w + nt2;
                    const unsigned short* bp =
                        Wef2 + (size_t)a*24576 + ((nt*3 + kt)*64 + l)*16;
                    bhalf8 bh = *(const bhalf8*)(bp);
                    bhalf8 bl = *(const bhalf8*)(bp + 8);
                    eacc[0][nt2] = __builtin_amdgcn_mfma_f32_16x16x32_bf16(ah0, bh, eacc[0][nt2], 0, 0, 0);
                    eacc[1][nt2] = __builtin_amdgcn_mfma_f32_16x16x32_bf16(ah1, bh, eacc[1][nt2], 0, 0, 0);
                    eacc[0][nt2] = __builtin_amdgcn_mfma_f32_16x16x32_bf16(ah0, bl, eacc[0][nt2], 0, 0, 0);
                    eacc[1][nt2] = __builtin_amdgcn_mfma_f32_16x16x32_bf16(ah1, bl, eacc[1][nt2], 0, 0, 0);
                    eacc[0][nt2] = __builtin_amdgcn_mfma_f32_16x16x32_bf16(al0, bh, eacc[0][nt2], 0, 0, 0);
                    eacc[1][nt2] = __builtin_amdgcn_mfma_f32_16x16x32_bf16(al1, bh, eacc[1][nt2], 0, 0, 0);
                }
            }
            float be0 = be[a*128 + 32*w + m];
            float be1 = be[a*128 + 32*w + 16 + m];
#pragma unroll
            for (int rt = 0; rt < 2; ++rt)
#pragma unroll
                for (int nt2 = 0; nt2 < 2; ++nt2) {
                    float bb = nt2 ? be1 : be0;
#pragma unroll
                    for (int r = 0; r < 4; ++r) {
                        float e = fmaxf(eacc[rt][nt2][r] + bb, 0.f);
                        int row = rt*16 + qd*4 + r;
                        int col = 32*w + nt2*16 + m;
                        unsigned short hh = f2bf(e);
                        sEnH[row*136 + col] = hh;
                        sEnL[row*136 + col] = f2bf(e - bf2f(hh));
                    }
                }
        }
        __syncthreads();

        // ---- logits ((hi+lo) f32 enc x bf16 t); stats in registers ----
        float alpha, pp;
        {
            const uint4* ehp = (const uint4*)(sEnH + b_l*136 + half*64);
            const uint4* elp = (const uint4*)(sEnL + b_l*136 + half*64);
            float part = 0.f;
#pragma unroll
            for (int i = 0; i < 8; ++i) {
                uint4 eh = ehp[i];
                uint4 el = elp[i];
                uint4 tt = tq[i];
                part += (bflo(eh.x)+bflo(el.x))*bflo(tt.x)
                      + (bfhi(eh.x)+bfhi(el.x))*bfhi(tt.x);
                part += (bflo(eh.y)+bflo(el.y))*bflo(tt.y)
                      + (bfhi(eh.y)+bfhi(el.y))*bfhi(tt.y);
                part += (bflo(eh.z)+bflo(el.z))*bflo(tt.z)
                      + (bfhi(eh.z)+bfhi(el.z))*bfhi(tt.z);
                part += (bflo(eh.w)+bflo(el.w))*bflo(tt.w)
                      + (bfhi(eh.w)+bfhi(el.w))*bfhi(tt.w);
            }
            part += __shfl_xor(part, 32);   // both halves now bit-identical
            float lg = part * 0.17677669529663687f;   // 1/sqrt(32)
            float mn = fmaxf(mR, lg);
            alpha = __expf(mR - mn);
            pp    = __expf(lg - mn);
            sR = sR*alpha + pp;
            mR = mn;
        }

        // ---- vals = relu(enc @ Wv + bv), split 3-term; online accumulate ----
        {
            f32x4 vacc[2][2] = {};
#pragma unroll
            for (int kt = 0; kt < 4; ++kt) {
                bhalf8 ah0 = *(const bhalf8*)(sEnH + m*136      + kt*32 + qd*8);
                bhalf8 ah1 = *(const bhalf8*)(sEnH + (16+m)*136 + kt*32 + qd*8);
                bhalf8 al0 = *(const bhalf8*)(sEnL + m*136      + kt*32 + qd*8);
                bhalf8 al1 = *(const bhalf8*)(sEnL + (16+m)*136 + kt*32 + qd*8);
#pragma unroll
                for (int nt2 = 0; nt2 < 2; ++nt2) {
                    int nt = 2*w + nt2;
                    const unsigned short* bp = Wvf2 + ((nt*4 + kt)*64 + l)*16;
                    bhalf8 bh = *(const bhalf8*)(bp);
                    bhalf8 bl = *(const bhalf8*)(bp + 8);
                    vacc[0][nt2] = __builtin_amdgcn_mfma_f32_16x16x32_bf16(ah0, bh, vacc[0][nt2], 0, 0, 0);
                    vacc[1][nt2] = __builtin_amdgcn_mfma_f32_16x16x32_bf16(ah1, bh, vacc[1][nt2], 0, 0, 0);
                    vacc[0][nt2] = __builtin_amdgcn_mfma_f32_16x16x32_bf16(ah0, bl, vacc[0][nt2], 0, 0, 0);
                    vacc[1][nt2] = __builtin_amdgcn_mfma_f32_16x16x32_bf16(ah1, bl, vacc[1][nt2], 0, 0, 0);
                    vacc[0][nt2] = __builtin_amdgcn_mfma_f32_16x16x32_bf16(al0, bh, vacc[0][nt2], 0, 0, 0);
                    vacc[1][nt2] = __builtin_amdgcn_mfma_f32_16x16x32_bf16(al1, bh, vacc[1][nt2], 0, 0, 0);
                }
            }
#pragma unroll
            for (int rt = 0; rt < 2; ++rt)
#pragma unroll
                for (int r = 0; r < 4; ++r) {
                    int row = rt*16 + qd*4 + r;
                    float al = __shfl(alpha, row);
                    float p  = __shfl(pp, row);
#pragma unroll
                    for (int nt2 = 0; nt2 < 2; ++nt2) {
                        float bb = nt2 ? bv1 : bv0;
                        o4[rt][nt2][r] = o4[rt][nt2][r]*al
                                       + p*fmaxf(vacc[rt][nt2][r] + bb, 0.f);
                    }
                }
        }
    }
    __syncthreads();   // all sEn reads done; sOv overwrites union region

    // ---- normalize (1/s via shfl) and dump ov to sOv f32 (stride 132) ----
    {
        float rinv = 1.0f / sR;
#pragma unroll
        for (int rt = 0; rt < 2; ++rt)
#pragma unroll
            for (int r = 0; r < 4; ++r) {
                int row = rt*16 + qd*4 + r;
                float inv = __shfl(rinv, row);
#pragma unroll
                for (int nt2 = 0; nt2 < 2; ++nt2)
                    sOv[row*132 + 32*w + nt2*16 + m] = o4[rt][nt2][r]*inv;
            }
    }
    __syncthreads();

    // ---- final: x3o = ov @ w3_others (f32); out = relu(x3s+x3o).Wout + bout
    {
        float acc[2][4] = {};
#pragma unroll 4
        for (int k = 0; k < 128; ++k) {
            float4 w4 = *(const float4*)(w3_others + k*64 + c0);
            float a0 = sOv[(rg*2+0)*132 + k];
            float a1 = sOv[(rg*2+1)*132 + k];
            acc[0][0] += a0*w4.x; acc[0][1] += a0*w4.y; acc[0][2] += a0*w4.z; acc[0][3] += a0*w4.w;
            acc[1][0] += a1*w4.x; acc[1][1] += a1*w4.y; acc[1][2] += a1*w4.z; acc[1][3] += a1*w4.w;
        }
        float4 wo = *(const float4*)(Wout + c0);
        float bo = bout[0];
#pragma unroll
        for (int i = 0; i < 2; ++i) {
            float p = fmaxf(acc[i][0] + x3s[i][0], 0.f) * wo.x
                    + fmaxf(acc[i][1] + x3s[i][1], 0.f) * wo.y
                    + fmaxf(acc[i][2] + x3s[i][2], 0.f) * wo.z
                    + fmaxf(acc[i][3] + x3s[i][3], 0.f) * wo.w;
#pragma unroll
            for (int off = 1; off < 16; off <<= 1)
                p += __shfl_xor(p, off);
            if (cg == 0) out[b0 + rg*2 + i] = p + bo;
        }
    }
}

extern "C" void kernel_launch(void* const* d_in, const int* in_sizes, int n_in,
                              void* d_out, int out_size, void* d_ws, size_t ws_size,
                              hipStream_t stream) {
    (void)in_sizes; (void)n_in; (void)out_size; (void)ws_size;
    const float* state_one    = (const float*)d_in[0];
    const float* act_one      = (const float*)d_in[1];
    const float* state_others = (const float*)d_in[2];
    const float* act_others   = (const float*)d_in[3];
    const float* W1           = (const float*)d_in[4];
    const float* b1           = (const float*)d_in[5];
    const float* W2           = (const float*)d_in[6];
    const float* b2           = (const float*)d_in[7];
    const float* w3_self      = (const float*)d_in[8];
    const float* We           = (const float*)d_in[9];
    const float* be           = (const float*)d_in[10];
    const float* Wk           = (const float*)d_in[11];
    const float* Wq           = (const float*)d_in[12];
    const float* Wv           = (const float*)d_in[13];
    const float* bv           = (const float*)d_in[14];
    const float* w3_others    = (const float*)d_in[15];
    const float* Wout         = (const float*)d_in[16];
    const float* bout         = (const float*)d_in[17];
    float* out = (float*)d_out;

    unsigned short* Mf2  = (unsigned short*)d_ws;                    // 131072 B
    unsigned short* Wef2 = (unsigned short*)((char*)d_ws + 131072);  // 344064 B
    unsigned short* Wvf2 = (unsigned short*)((char*)d_ws + 475136);  // 65536 B

    fold_M_frag<<<128, 256, 0, stream>>>(Wk, Wq, Mf2);
    conv_We<<<336, 256, 0, stream>>>(We, Wef2);
    conv_Wv<<<64, 256, 0, stream>>>(Wv, Wvf2);
    fused_critic<<<BTOT/TB, 256, 0, stream>>>(
        state_one, act_one, state_others, act_others,
        W1, b1, W2, b2, w3_self, be, bv, w3_others, Wout, bout,
        Mf2, Wef2, Wvf2, out);
}